// Round 4
// baseline (752.862 us; speedup 1.0000x reference)
//
#include <hip/hip_runtime.h>

// Dims: B=2, L=32, C=32, S=64, W=64, R=32, MH=32. BL=64, SW=4096.
//
// Whole pipeline in ONE kernel with in-kernel grid barriers:
//  A: hs = x ×_c pW (MFMA) + DFT coeff mats + weff     (1124 units)
//  B: zq (2 MFMA GEMMs per (bl,c)) + MLP lam/gam       (2112 units)
//  C: 4-way split-chain scan over l                    (1024 units)
//  D: rec (2 MFMA GEMMs) -> hsp                        (2048 units)
//  E: MFMA 3x3 conv, 2-row slabs                       (2048 units)
//  F: LN + residual out                                (2048 units)
// Grid is occupancy-clamped so all blocks are co-resident -> the manual
// sense-reversal barrier (agent-scope atomics + __threadfence) is safe.

typedef __attribute__((ext_vector_type(8))) short short8;
typedef __attribute__((ext_vector_type(4))) float floatx4;

__device__ __forceinline__ unsigned pack_bf16(float re, float im) {
  unsigned a = __float_as_uint(re), b = __float_as_uint(im);
  a = (a + 0x7FFFu + ((a >> 16) & 1u)) >> 16;
  b = (b + 0x7FFFu + ((b >> 16) & 1u)) >> 16;
  return a | (b << 16);
}
__device__ __forceinline__ unsigned short bf16r(float v) {
  unsigned a = __float_as_uint(v);
  return (unsigned short)((a + 0x7FFFu + ((a >> 16) & 1u)) >> 16);
}

struct KP {
  const float *x, *listT, *plb, *dmod, *W1, *b1, *W2, *b2, *fscale;
  const float *U_re, *U_im, *V_re, *V_im, *pWr, *pWi;
  const float *projc_w, *convr_w, *convi_w, *ln_w, *ln_b;
  float* out;
  unsigned *hs, *zqA, *recA, *recB, *Wtb;
  float* ctxp;
  float2 *zq, *lam;
  float* gam;
  unsigned* zs;
  unsigned short* convout;
  float2* stats;
  int* bar;
  int zst;
};

// Device-wide sense-reversal barrier. Requires all blocks co-resident
// (guaranteed host-side via occupancy clamp). bar[0]=count, bar[1]=gen,
// both zeroed by a hipMemsetAsync before launch.
__device__ __forceinline__ void gbar(int* bar) {
  __syncthreads();
  if (threadIdx.x == 0) {
    __threadfence();  // release: drain + L2 writeback (agent scope)
    int g = __hip_atomic_load(bar + 1, __ATOMIC_RELAXED, __HIP_MEMORY_SCOPE_AGENT);
    int v = __hip_atomic_fetch_add(bar, 1, __ATOMIC_ACQ_REL, __HIP_MEMORY_SCOPE_AGENT);
    if (v == (int)gridDim.x - 1) {
      __hip_atomic_store(bar, 0, __ATOMIC_RELAXED, __HIP_MEMORY_SCOPE_AGENT);
      __hip_atomic_store(bar + 1, g + 1, __ATOMIC_RELEASE, __HIP_MEMORY_SCOPE_AGENT);
    } else {
      while (__hip_atomic_load(bar + 1, __ATOMIC_RELAXED, __HIP_MEMORY_SCOPE_AGENT) == g)
        __builtin_amdgcn_s_sleep(8);
    }
    __threadfence();  // acquire: invalidate L1/L2 before consuming
  }
  __syncthreads();
}

__global__ __launch_bounds__(256, 4) void k_all(KP p) {
  __shared__ __align__(16) char smem[33792];
  const int tid = threadIdx.x;

  // ================================================= Phase A: mix/DFT/weff
  for (int wk = blockIdx.x; wk < 1124; wk += gridDim.x) {
    if (wk < 1024) {                          // ---- mix body
      unsigned* xb_s = (unsigned*)smem;                     // [256*20] 20 KB
      float(*red)[16][2] = (float(*)[16][2])(smem + 20480); // 2 KB
      unsigned* outb = (unsigned*)smem;                     // [32][260] 33 KB
      const int bl = wk >> 4;
      const int seg = wk & 15;
      const int pxbase = seg * 256;
      const float* xb = p.x + (size_t)bl * 131072 + pxbase;
      float csa = 0.f, csb = 0.f;
#pragma unroll
      for (int t = 0; t < 4; ++t) {
        int i = t * 256 + tid;
        int c2 = i & 15, g4 = i >> 4;
        float4 a = *(const float4*)(xb + (2 * c2) * 4096 + g4 * 4);
        float4 b = *(const float4*)(xb + (2 * c2 + 1) * 4096 + g4 * 4);
        csa += a.x + a.y + a.z + a.w;
        csb += b.x + b.y + b.z + b.w;
#pragma unroll
        for (int j = 0; j < 4; ++j) {
          int px = g4 * 4 + j;
          xb_s[px * 20 + (((c2 >> 2) ^ (px & 3)) << 2) + (c2 & 3)] =
              pack_bf16(((const float*)&a)[j], ((const float*)&b)[j]);
        }
      }
      red[tid & 15][tid >> 4][0] = csa;
      red[tid & 15][tid >> 4][1] = csb;
      const int lane = tid & 63, wv = tid >> 6;
      const int qd = lane >> 4, ln = lane & 15;
      short8 arL, aiL, arH, aiH;
#pragma unroll
      for (int j = 0; j < 8; ++j) {
        int ci = qd * 8 + j;
        ((short*)&arL)[j] = (short)bf16r(p.pWr[ci * 32 + ln]);
        ((short*)&aiL)[j] = (short)bf16r(p.pWi[ci * 32 + ln]);
        ((short*)&arH)[j] = (short)bf16r(p.pWr[ci * 32 + 16 + ln]);
        ((short*)&aiH)[j] = (short)bf16r(p.pWi[ci * 32 + 16 + ln]);
      }
      __syncthreads();
      if (tid < 32) {
        int c2 = tid >> 1, part = tid & 1;
        float s = 0.f;
#pragma unroll
        for (int w = 0; w < 16; ++w) s += red[c2][w][part];
        p.ctxp[(bl * 16 + seg) * 32 + 2 * c2 + part] = s;
      }
      floatx4 RL[4], IL[4], RH[4], IH[4];
#pragma unroll
      for (int pt = 0; pt < 4; ++pt) {
        int pxt = wv * 4 + pt;
        int pxl = pxt * 16 + ln;
        short8 bfr = *(const short8*)&xb_s[pxl * 20 + ((qd ^ (pxl & 3)) << 2)];
        floatx4 z4 = {0.f, 0.f, 0.f, 0.f};
        RL[pt] = __builtin_amdgcn_mfma_f32_16x16x32_bf16(arL, bfr, z4, 0, 0, 0);
        IL[pt] = __builtin_amdgcn_mfma_f32_16x16x32_bf16(aiL, bfr, z4, 0, 0, 0);
        RH[pt] = __builtin_amdgcn_mfma_f32_16x16x32_bf16(arH, bfr, z4, 0, 0, 0);
        IH[pt] = __builtin_amdgcn_mfma_f32_16x16x32_bf16(aiH, bfr, z4, 0, 0, 0);
      }
      __syncthreads();              // xb_s dead; reuse as outb
#pragma unroll
      for (int pt = 0; pt < 4; ++pt) {
        int px = (wv * 4 + pt) * 16 + ln;
#pragma unroll
        for (int j = 0; j < 4; ++j) {
          outb[(qd * 4 + j) * 260 + px] = pack_bf16(RL[pt][j], IL[pt][j]);
          outb[(16 + qd * 4 + j) * 260 + px] = pack_bf16(RH[pt][j], IH[pt][j]);
        }
      }
      __syncthreads();
      unsigned* ho = p.hs + (size_t)bl * 131072 + pxbase;
      const int px4 = tid & 63, dg = tid >> 6;
#pragma unroll
      for (int dd = 0; dd < 8; ++dd) {
        int d = dg * 8 + dd;
        uint4 v = *(const uint4*)&outb[d * 260 + px4 * 4];
        *(uint4*)(ho + d * 4096 + px4 * 4) = v;
      }
    } else if (wk < 1088) {                   // ---- DFT body
      float2* A2 = (float2*)smem;             // [2048] 16 KB
      float2* tw = (float2*)(smem + 16384);   // [64]
      const int id = wk - 1024;
      const int c = id >> 1, src = id & 1;    // 0=U(plus), 1=V(minus)
      const float* Ar = (src ? p.V_re : p.U_re) + c * 2048;
      const float* Ai = (src ? p.V_im : p.U_im) + c * 2048;
      if (tid < 64) {
        float sa, ca;
        sincosf((float)tid * 0.09817477042468103f, &sa, &ca);
        tw[tid] = make_float2(ca, sa);
      }
#pragma unroll
      for (int t = 0; t < 8; ++t) {
        int idx = t * 256 + tid;
        A2[idx] = make_float2(Ar[idx], Ai[idx]);
      }
      __syncthreads();
      const int kw = tid >> 2, mg = tid & 3;
      float sr[8] = {0.f, 0.f, 0.f, 0.f, 0.f, 0.f, 0.f, 0.f};
      float si[8] = {0.f, 0.f, 0.f, 0.f, 0.f, 0.f, 0.f, 0.f};
#pragma unroll 4
      for (int n = 0; n < 64; ++n) {
        float2 w = tw[(kw * n) & 63];
        float ws = src ? -w.y : w.y;
#pragma unroll
        for (int t4 = 0; t4 < 4; ++t4) {
          float4 q = *(const float4*)&A2[n * 32 + mg * 8 + t4 * 2];
          sr[2 * t4]     += q.x * w.x - q.y * ws;
          si[2 * t4]     += q.x * ws + q.y * w.x;
          sr[2 * t4 + 1] += q.z * w.x - q.w * ws;
          si[2 * t4 + 1] += q.z * ws + q.w * w.x;
        }
      }
#pragma unroll
      for (int j = 0; j < 8; ++j) {
        float r = sr[j] * 0.125f, i2 = si[j] * 0.125f;
        int m = mg * 8 + j;
        unsigned p_ri  = pack_bf16(r, i2);
        unsigned p_rmi = pack_bf16(r, -i2);
        unsigned p_ir  = pack_bf16(i2, r);
        unsigned p_mir = pack_bf16(-i2, r);
        if (src == 0) {                       // F+ . U
          p.zqA[((c * 4 + 2) * 32 + m) * 64 + kw] = p_ri;
          p.zqA[((c * 4 + 3) * 32 + m) * 64 + kw] = p_mir;
          p.recA[((c * 2 + 0) * 64 + kw) * 32 + m] = p_rmi;
          p.recA[((c * 2 + 1) * 64 + kw) * 32 + m] = p_ir;
        } else {                              // F- . V
          p.zqA[((c * 4 + 0) * 32 + m) * 64 + kw] = p_rmi;
          p.zqA[((c * 4 + 1) * 32 + m) * 64 + kw] = p_ir;
          p.recB[((c * 2 + 0) * 64 + kw) * 32 + m] = p_ri;
          p.recB[((c * 2 + 1) * 64 + kw) * 32 + m] = p_mir;
        }
      }
    } else {                                  // ---- weff body
      int gid = (wk - 1088) * 256 + tid;
      if (gid < 9216) {
        int co = gid / 288;
        int r2 = gid - co * 288;
        int tap = r2 >> 5, ci = r2 & 31;
        float sr = 0.f, si = 0.f;
        for (int m = 0; m < 32; ++m) {
          sr += p.projc_w[co * 64 + m]      * p.convr_w[(m * 32 + ci) * 9 + tap];
          si += p.projc_w[co * 64 + 32 + m] * p.convi_w[(m * 32 + ci) * 9 + tap];
        }
        p.Wtb[gid] = pack_bf16(sr, si);
      }
    }
    __syncthreads();
  }
  gbar(p.bar);

  // ================================================= Phase B: zq + MLP
  for (int wk = blockIdx.x; wk < 2112; wk += gridDim.x) {
    if (wk < 2048) {                          // ---- zq body
      unsigned* HsB = (unsigned*)smem;        // 16 KB
      unsigned* T2 = HsB + 4096;              // 8 KB
      const int blc = wk;
      const int c = blc & 31;
      const int lane = tid & 63, wv = tid >> 6;
      const int qd = lane >> 4, ln = lane & 15;
      const int mt = wv >> 1, nth = wv & 1;
      {
        const uint4* hp = (const uint4*)(p.hs + (size_t)blc * 4096);
#pragma unroll
        for (int it = 0; it < 4; ++it) {
          int i4 = tid + it * 256;
          uint4 v = hp[i4];
          int s = i4 >> 4, w4 = i4 & 15;
          *(uint4*)&HsB[s * 64 + ((w4 ^ (s & 15)) << 2)] = v;
        }
      }
      const short* zA = (const short*)p.zqA + (size_t)c * 4 * 32 * 128;
      short8 a1[4], a2[4], a3[4], a4[4];
#pragma unroll
      for (int t = 0; t < 4; ++t) {
        int row = mt * 16 + ln;
        a1[t] = *(const short8*)(zA + (0 * 32 + row) * 128 + t * 32 + qd * 8);
        a2[t] = *(const short8*)(zA + (1 * 32 + row) * 128 + t * 32 + qd * 8);
        a3[t] = *(const short8*)(zA + (2 * 32 + row) * 128 + t * 32 + qd * 8);
        a4[t] = *(const short8*)(zA + (3 * 32 + row) * 128 + t * 32 + qd * 8);
      }
      __syncthreads();
#pragma unroll
      for (int nti = 0; nti < 2; ++nti) {
        int nt = nth * 2 + nti;
        int n = nt * 16 + ln;
        floatx4 accr = {0.f, 0.f, 0.f, 0.f}, acci = {0.f, 0.f, 0.f, 0.f};
#pragma unroll
        for (int t = 0; t < 4; ++t) {
          short8 b = *(const short8*)&HsB[n * 64 + (((4 * t + qd) ^ (n & 15)) << 2)];
          accr = __builtin_amdgcn_mfma_f32_16x16x32_bf16(a1[t], b, accr, 0, 0, 0);
          acci = __builtin_amdgcn_mfma_f32_16x16x32_bf16(a2[t], b, acci, 0, 0, 0);
        }
#pragma unroll
        for (int j = 0; j < 4; ++j) {
          int q = mt * 16 + qd * 4 + j;
          int s = n;
          T2[q * 64 + (((s >> 2) ^ (q & 15)) << 2) + (s & 3)] =
              pack_bf16(accr[j], acci[j]);
        }
      }
      __syncthreads();
      {
        const int mt2 = wv >> 1, nt2 = wv & 1;
        int n = nt2 * 16 + ln;
        floatx4 zr = {0.f, 0.f, 0.f, 0.f}, zi = {0.f, 0.f, 0.f, 0.f};
#pragma unroll
        for (int t = 0; t < 4; ++t) {
          short8 b = *(const short8*)&T2[n * 64 + (((4 * t + qd) ^ (n & 15)) << 2)];
          zr = __builtin_amdgcn_mfma_f32_16x16x32_bf16(a3[t], b, zr, 0, 0, 0);
          zi = __builtin_amdgcn_mfma_f32_16x16x32_bf16(a4[t], b, zi, 0, 0, 0);
        }
        float2* zo = p.zq + (size_t)blc * 1024;
#pragma unroll
        for (int j = 0; j < 4; ++j) {
          int r = mt2 * 16 + qd * 4 + j;
          zo[r * 32 + n] = make_float2(zr[j], zi[j]);
        }
      }
    } else {                                  // ---- MLP body
      float* mid_s = (float*)(smem + 24576);
      float* ctxs = mid_s + 32;
      int bl = wk - 2048;
      float dt = p.listT[bl];
      if (tid < 32) {
        float s = 0.f;
#pragma unroll
        for (int sg = 0; sg < 16; ++sg) s += p.ctxp[(bl * 16 + sg) * 32 + tid];
        ctxs[tid] = s * (1.f / 4096.f);
      }
      __syncthreads();
      if (tid < 32) {
        float a = p.b1[tid];
        for (int j = 0; j < 32; ++j) a += ctxs[j] * p.W1[j * 32 + tid];
        a += dt * p.W1[1024 + tid];
        mid_s[tid] = tanhf(a);
      }
      __syncthreads();
      float fs = p.fscale[0];
#pragma unroll
      for (int u = 0; u < 4; ++u) {
        int cr = u * 256 + tid;
        int col = cr * 2;
        float m0 = p.b2[col], m1 = p.b2[col + 1];
        for (int h = 0; h < 32; ++h) {
          float mh = mid_s[h];
          float2 w2 = *(const float2*)&p.W2[h * 2048 + col];
          m0 += mh * w2.x;
          m1 += mh * w2.y;
        }
        float dnu = fs * tanhf(m0);
        float dth = fs * tanhf(m1);
        float nub = expf(p.plb[cr] + p.dmod[cr]);
        float thb = expf(p.plb[1024 + cr] + p.dmod[1024 + cr]);
        float nut = fmaxf(nub * dt + dnu, 1e-6f);
        float tht = thb * dt + dth;
        float e = expf(-nut);
        float sa, ca;
        sincosf(tht, &sa, &ca);
        float g = sqrtf(fmaxf(1.f - expf(-2.f * nut), 1e-12f));
        int o = bl * 1024 + cr;
        p.lam[o] = make_float2(e * ca, e * sa);
        p.gam[o] = g;
      }
    }
    __syncthreads();
  }
  gbar(p.bar);

  // ================================================= Phase C: scan
  for (int wk = blockIdx.x; wk < 1024; wk += gridDim.x) {
    float2* se = (float2*)smem;               // [4][64]
    float2* pe = se + 256;
    float2* cr_s = pe + 256;
    const int bc = wk >> 4;
    const int b = bc >> 5, c = bc & 31;
    const int rq0 = (wk & 15) * 64;
    const int seg = tid >> 6, u = tid & 63;
    const int rq = rq0 + u, r = rq >> 5;
    const int t0 = seg * 8;
    float2 vv[8], ll[8];
    float gg[8];
#pragma unroll
    for (int i = 0; i < 8; ++i) {
      int t = b * 32 + t0 + i;
      vv[i] = p.zq[((size_t)t * 32 + c) * 1024 + rq];
      ll[i] = p.lam[t * 1024 + c * 32 + r];
      gg[i] = p.gam[t * 1024 + c * 32 + r];
    }
    float2 s = make_float2(0.f, 0.f), P = make_float2(1.f, 0.f);
    float2 zloc[8], Ps[8];
#pragma unroll
    for (int i = 0; i < 8; ++i) {
      float2 lm = ll[i];
      float nr = lm.x * s.x - lm.y * s.y + gg[i] * vv[i].x;
      float ni = lm.x * s.y + lm.y * s.x + gg[i] * vv[i].y;
      s = make_float2(nr, ni);
      float pr = P.x * lm.x - P.y * lm.y;
      float pi = P.x * lm.y + P.y * lm.x;
      P = make_float2(pr, pi);
      zloc[i] = s;
      Ps[i] = P;
    }
    se[seg * 64 + u] = s;
    pe[seg * 64 + u] = P;
    __syncthreads();
    if (tid < 64) {
      float2 c1 = se[u];
      float2 p1 = pe[64 + u], s1 = se[64 + u];
      float2 c2 = make_float2(s1.x + p1.x * c1.x - p1.y * c1.y,
                              s1.y + p1.x * c1.y + p1.y * c1.x);
      float2 p2 = pe[128 + u], s2 = se[128 + u];
      float2 c3 = make_float2(s2.x + p2.x * c2.x - p2.y * c2.y,
                              s2.y + p2.x * c2.y + p2.y * c2.x);
      cr_s[u] = make_float2(0.f, 0.f);
      cr_s[64 + u] = c1;
      cr_s[128 + u] = c2;
      cr_s[192 + u] = c3;
    }
    __syncthreads();
    float2 cr = cr_s[seg * 64 + u];
#pragma unroll
    for (int i = 0; i < 8; ++i) {
      float zr = zloc[i].x + Ps[i].x * cr.x - Ps[i].y * cr.y;
      float zi = zloc[i].y + Ps[i].x * cr.y + Ps[i].y * cr.x;
      size_t idx = ((size_t)(b * 32 + t0 + i) * 32 + c) * 1024 + rq;
      p.zs[idx * p.zst] = pack_bf16(zr, zi);
    }
    __syncthreads();
  }
  gbar(p.bar);

  // ================================================= Phase D: rec
  for (int wk = blockIdx.x; wk < 2048; wk += gridDim.x) {
    unsigned* zB = (unsigned*)smem;           // 4 KB
    unsigned* P = zB + 1024;                  // 8 KB
    const int blc = wk;
    const int c = blc & 31;
    const int lane = tid & 63, wv = tid >> 6;
    const int qd = lane >> 4, ln = lane & 15;
    {
      const unsigned* zp = p.zs + (size_t)blc * 1024 * p.zst;
#pragma unroll
      for (int it = 0; it < 4; ++it) {
        int i = tid + it * 256;
        unsigned pv = zp[(size_t)i * p.zst];
        int r = i >> 5, q = i & 31;
        zB[q * 32 + (((r >> 2) ^ (q & 7)) << 2) + (r & 3)] = pv;
      }
    }
    const short* rA = (const short*)p.recA + (size_t)c * 2 * 64 * 64;
    short8 a5[2], a6[2];
#pragma unroll
    for (int t = 0; t < 2; ++t) {
      int row = wv * 16 + ln;
      a5[t] = *(const short8*)(rA + (0 * 64 + row) * 64 + t * 32 + qd * 8);
      a6[t] = *(const short8*)(rA + (1 * 64 + row) * 64 + t * 32 + qd * 8);
    }
    __syncthreads();
#pragma unroll
    for (int nt = 0; nt < 2; ++nt) {
      int n = nt * 16 + ln;
      floatx4 pr = {0.f, 0.f, 0.f, 0.f}, pi = {0.f, 0.f, 0.f, 0.f};
#pragma unroll
      for (int t = 0; t < 2; ++t) {
        short8 b = *(const short8*)&zB[n * 32 + (((4 * t + qd) ^ (n & 7)) << 2)];
        pr = __builtin_amdgcn_mfma_f32_16x16x32_bf16(a5[t], b, pr, 0, 0, 0);
        pi = __builtin_amdgcn_mfma_f32_16x16x32_bf16(a6[t], b, pi, 0, 0, 0);
      }
#pragma unroll
      for (int j = 0; j < 4; ++j) {
        int s = wv * 16 + qd * 4 + j;
        int q = n;
        P[s * 32 + (((q >> 2) ^ (s & 7)) << 2) + (q & 3)] = pack_bf16(pr[j], pi[j]);
      }
    }
    __syncthreads();
    const short* rB = (const short*)p.recB + (size_t)c * 2 * 64 * 64;
    short8 pa[2];
#pragma unroll
    for (int t = 0; t < 2; ++t) {
      int row = wv * 16 + ln;
      pa[t] = *(const short8*)&P[row * 32 + (((4 * t + qd) ^ (row & 7)) << 2)];
    }
#pragma unroll
    for (int nt = 0; nt < 4; ++nt) {
      int n = nt * 16 + ln;
      floatx4 hr = {0.f, 0.f, 0.f, 0.f}, hi = {0.f, 0.f, 0.f, 0.f};
#pragma unroll
      for (int t = 0; t < 2; ++t) {
        short8 b5 = *(const short8*)(rB + (0 * 64 + n) * 64 + t * 32 + qd * 8);
        short8 b6 = *(const short8*)(rB + (1 * 64 + n) * 64 + t * 32 + qd * 8);
        hr = __builtin_amdgcn_mfma_f32_16x16x32_bf16(pa[t], b5, hr, 0, 0, 0);
        hi = __builtin_amdgcn_mfma_f32_16x16x32_bf16(pa[t], b6, hi, 0, 0, 0);
      }
      unsigned* ho = p.hs + (size_t)blc * 4096;   // hsp aliases hs
#pragma unroll
      for (int j = 0; j < 4; ++j) {
        int s = wv * 16 + qd * 4 + j;
        ho[s * 64 + n] = pack_bf16(hr[j], hi[j]);
      }
    }
    __syncthreads();
  }
  gbar(p.bar);

  // ================================================= Phase E: conv (2-row slabs)
  for (int wk = blockIdx.x; wk < 2048; wk += gridDim.x) {
    unsigned* lds_in = (unsigned*)smem;       // 4*66*32 u32 = 33792 B
    const int bl = wk >> 5;
    const int slab = wk & 31;
    const int y0 = slab * 2;
    {                                         // zero x-border cells
      int ci = tid & 31, j = tid >> 5;        // j 0..7
      int yi = j >> 1, xi = (j & 1) ? 65 : 0;
      int slot = (ci >> 2) ^ (xi & 7);
      lds_in[(yi * 66 + xi) * 32 + slot * 4 + (ci & 3)] = 0u;
    }
#pragma unroll
    for (int t = 0; t < 8; ++t) {             // interior staging: 4 rows
      int i = t * 256 + tid;
      int ci = i & 31;
      int j = i >> 5;                         // 0..63
      int yi = j >> 4, x4 = j & 15;
      int y = y0 + yi - 1;
      uint4 v = make_uint4(0u, 0u, 0u, 0u);
      if ((unsigned)y < 64u)
        v = *(const uint4*)(p.hs + (((size_t)bl * 32 + ci) * 64 + y) * 64 + x4 * 4);
      int xb = 1 + x4 * 4;
#pragma unroll
      for (int jj = 0; jj < 4; ++jj) {
        int xi = xb + jj;
        int slot = (ci >> 2) ^ (xi & 7);
        lds_in[(yi * 66 + xi) * 32 + slot * 4 + (ci & 3)] =
            ((const unsigned*)&v)[jj];
      }
    }
    __syncthreads();
    const int lane = tid & 63;
    const int wv = tid >> 6;                  // x-quarter
    const int co = lane & 15;
    const int qd = lane >> 4;
    const int x0 = wv * 16;
    const int xl = lane & 15;
    for (int cog = 0; cog < 2; ++cog) {
      short8 bW[18];
      {
        const short* wp = (const short*)p.Wtb + ((cog * 16 + co) * 9) * 64 + qd * 8;
#pragma unroll
        for (int tap = 0; tap < 9; ++tap)
#pragma unroll
          for (int kk = 0; kk < 2; ++kk)
            bW[tap * 2 + kk] = *(const short8*)(wp + tap * 64 + kk * 32);
      }
      float sA = 0.f, s2A = 0.f;
      for (int ry = 0; ry < 2; ++ry) {
        floatx4 acc = {0.f, 0.f, 0.f, 0.f};
#pragma unroll
        for (int tap = 0; tap < 9; ++tap) {
          int dy = tap / 3, dx = tap - dy * 3;
          int yi = ry + dy;
          int xi = x0 + xl + dx;
#pragma unroll
          for (int kk = 0; kk < 2; ++kk) {
            int slot = ((kk << 2) | qd) ^ (xi & 7);
            const short8 a =
                *(const short8*)&lds_in[(yi * 66 + xi) * 32 + slot * 4];
            acc = __builtin_amdgcn_mfma_f32_16x16x32_bf16(a, bW[tap * 2 + kk],
                                                          acc, 0, 0, 0);
          }
        }
        size_t go = (((size_t)bl * 32 + cog * 16 + co) * 64 + (y0 + ry)) * 64 +
                    x0 + qd * 4;
        *(uint2*)(p.convout + go) =
            make_uint2(pack_bf16(acc[0], acc[1]), pack_bf16(acc[2], acc[3]));
#pragma unroll
        for (int j = 0; j < 4; ++j) {
          sA += acc[j];
          s2A += acc[j] * acc[j];
        }
      }
      sA += __shfl_down(sA, 32, 64);
      s2A += __shfl_down(s2A, 32, 64);
      sA += __shfl_down(sA, 16, 64);
      s2A += __shfl_down(s2A, 16, 64);
      if (lane < 16) {
        p.stats[((size_t)bl * 32 + cog * 16 + lane) * 128 + slab * 4 + wv] =
            make_float2(sA, s2A);
      }
    }
    __syncthreads();
  }
  gbar(p.bar);

  // ================================================= Phase F: LN + residual
  for (int wk = blockIdx.x; wk < 2048; wk += gridDim.x) {
    float* pp = (float*)smem;
    const int blc = wk;
    const uint2* cp = (const uint2*)(p.convout + (size_t)blc * 4096);
    const float4* xp = (const float4*)(p.x + (size_t)blc * 4096);
    const float4* lwp = (const float4*)p.ln_w;
    const float4* lbp = (const float4*)p.ln_b;
    float4* op = (float4*)(p.out + (size_t)blc * 4096);
    uint2 cv[4];
    float4 xv[4], lw[4], lb[4];
#pragma unroll
    for (int k = 0; k < 4; ++k) {             // hoist streaming loads
      int i = tid + k * 256;
      cv[k] = cp[i];
      xv[k] = xp[i];
      lw[k] = lwp[i];
      lb[k] = lbp[i];
    }
    float s = 0.f, s2 = 0.f;
    if (tid < 128) {
      float2 v = p.stats[(size_t)blc * 128 + tid];
      s = v.x;
      s2 = v.y;
    }
    s += __shfl_down(s, 32, 64);   s2 += __shfl_down(s2, 32, 64);
    s += __shfl_down(s, 16, 64);   s2 += __shfl_down(s2, 16, 64);
    s += __shfl_down(s, 8, 64);    s2 += __shfl_down(s2, 8, 64);
    s += __shfl_down(s, 4, 64);    s2 += __shfl_down(s2, 4, 64);
    s += __shfl_down(s, 2, 64);    s2 += __shfl_down(s2, 2, 64);
    s += __shfl_down(s, 1, 64);    s2 += __shfl_down(s2, 1, 64);
    if (tid < 128 && (tid & 63) == 0) {
      pp[(tid >> 6) * 2] = s;
      pp[(tid >> 6) * 2 + 1] = s2;
    }
    __syncthreads();
    if (tid == 0) {
      float ss = pp[0] + pp[2], ss2 = pp[1] + pp[3];
      float mu = ss * (1.f / 4096.f);
      float var = ss2 * (1.f / 4096.f) - mu * mu;
      pp[4] = mu;
      pp[5] = rsqrtf(var + 1e-5f);
    }
    __syncthreads();
    float mu = pp[4], rs = pp[5];
#pragma unroll
    for (int k = 0; k < 4; ++k) {
      int i = tid + k * 256;
      float c0 = __uint_as_float(cv[k].x << 16);
      float c1 = __uint_as_float(cv[k].x & 0xFFFF0000u);
      float c2 = __uint_as_float(cv[k].y << 16);
      float c3 = __uint_as_float(cv[k].y & 0xFFFF0000u);
      float4 o;
      o.x = xv[k].x + (c0 - mu) * rs * lw[k].x + lb[k].x;
      o.y = xv[k].y + (c1 - mu) * rs * lw[k].y + lb[k].y;
      o.z = xv[k].z + (c2 - mu) * rs * lw[k].z + lb[k].z;
      o.w = xv[k].w + (c3 - mu) * rs * lw[k].w + lb[k].w;
      op[i] = o;
    }
    __syncthreads();
  }
}

// ------------------------------------------------------------------- launch
extern "C" void kernel_launch(void* const* d_in, const int* in_sizes, int n_in,
                              void* d_out, int out_size, void* d_ws,
                              size_t ws_size, hipStream_t stream) {
  const float* x       = (const float*)d_in[0];
  const float* listT   = (const float*)d_in[1];
  const float* plb     = (const float*)d_in[2];
  const float* dmod    = (const float*)d_in[3];
  const float* fm_W1   = (const float*)d_in[4];
  const float* fm_b1   = (const float*)d_in[5];
  const float* fm_W2   = (const float*)d_in[6];
  const float* fm_b2   = (const float*)d_in[7];
  const float* fscale  = (const float*)d_in[8];
  const float* U_re    = (const float*)d_in[9];
  const float* U_im    = (const float*)d_in[10];
  const float* V_re    = (const float*)d_in[11];
  const float* V_im    = (const float*)d_in[12];
  const float* pW_re   = (const float*)d_in[13];
  const float* pW_im   = (const float*)d_in[14];
  // d_in[15..16] pb_re/pb_im: cropped out, no effect
  const float* convr_w = (const float*)d_in[17];
  // convr_b/convi_b/projc_b (18,20,22): constant over [S,W] -> cancel in LN
  const float* convi_w = (const float*)d_in[19];
  const float* projc_w = (const float*)d_in[21];
  const float* ln_w    = (const float*)d_in[23];
  const float* ln_b    = (const float*)d_in[24];
  float* out = (float*)d_out;

  float* wsf = (float*)d_ws;
  // R0a [0, 8388608): hs (packed bf16) -> later hsp (alias)
  unsigned* hs = (unsigned*)wsf;
  // R0b [8388608, 16777216): coeff mats (dead before conv), then convout+stats
  unsigned* zqAp  = (unsigned*)(wsf + 8388608);           // 262144 u32
  unsigned* recAp = (unsigned*)(wsf + 8388608 + 262144);  // 131072 u32
  unsigned* recBp = (unsigned*)(wsf + 8388608 + 393216);  // 131072 u32
  unsigned short* convout = (unsigned short*)(wsf + 8388608);  // 8388608 u16
  float2*   stats = (float2*)(wsf + 12582912);            // 262144 float2
  float2*   zq  = (float2*)(wsf + 16777216);              // 4,194,304 fl
  size_t off = 16777216 + 4194304;
  const size_t tail = 238608;  // lam+gam+ctxp+Wtb+bar
  unsigned* zs;
  int zst;
  size_t off2;
  if (ws_size >= (off + 2097152 + tail) * 4) {
    zs = (unsigned*)(wsf + off); zst = 1; off2 = off + 2097152;
  } else {
    zs = (unsigned*)zq; zst = 2; off2 = off;
  }
  float2*   lam  = (float2*)(wsf + off2);                 // 131,072 fl
  float*    gam  = wsf + off2 + 131072;                   // 65,536 fl
  float*    ctxp = wsf + off2 + 196608;                   // 32,768 fl
  unsigned* Wtb  = (unsigned*)(wsf + off2 + 229376);      // 9,216 u32
  int*      bar  = (int*)(wsf + off2 + 238592);           // 2 ints

  static int NB = 0;
  if (NB == 0) {
    int perCU = 0;
    if (hipOccupancyMaxActiveBlocksPerMultiprocessor(&perCU, k_all, 256, 0) !=
            hipSuccess ||
        perCU < 1)
      perCU = 2;
    int numCU = 256;
    hipDeviceProp_t prop;
    int dev = 0;
    if (hipGetDevice(&dev) == hipSuccess &&
        hipGetDeviceProperties(&prop, dev) == hipSuccess &&
        prop.multiProcessorCount > 0)
      numCU = prop.multiProcessorCount;
    long cap = (long)perCU * numCU;
    NB = (int)(cap > 2048 ? 2048 : cap);
  }

  KP p;
  p.x = x; p.listT = listT; p.plb = plb; p.dmod = dmod;
  p.W1 = fm_W1; p.b1 = fm_b1; p.W2 = fm_W2; p.b2 = fm_b2; p.fscale = fscale;
  p.U_re = U_re; p.U_im = U_im; p.V_re = V_re; p.V_im = V_im;
  p.pWr = pW_re; p.pWi = pW_im;
  p.projc_w = projc_w; p.convr_w = convr_w; p.convi_w = convi_w;
  p.ln_w = ln_w; p.ln_b = ln_b;
  p.out = out;
  p.hs = hs; p.zqA = zqAp; p.recA = recAp; p.recB = recBp; p.Wtb = Wtb;
  p.ctxp = ctxp; p.zq = zq; p.lam = lam; p.gam = gam;
  p.zs = zs; p.convout = convout; p.stats = stats;
  p.bar = bar; p.zst = zst;

  hipMemsetAsync(bar, 0, 8, stream);
  k_all<<<NB, 256, 0, stream>>>(p);
}

// Round 5
// 264.716 us; speedup vs baseline: 2.8440x; 2.8440x over previous
//
#include <hip/hip_runtime.h>

// Dims: B=2, L=32, C=32, S=64, W=64, R=32, MH=32. BL=64, SW=4096.
//
// 4-dispatch pipeline:
//  k_mixprep: hs = x ×_c pW (MFMA, blocks 64..1087) + ctx/MLP->lam,gam
//             (blocks 0..63) + DFT coeff mats (1088..1151) + weff (1152..1187)
//  k_mid:     per-(b,c) block (64 x 512thr): for each l: zq GEMMs ->
//             sequential scan in regs -> rec GEMMs. No zq/zs global bufs.
//  k_conv:    MFMA 3x3 conv (R2 version)
//  k_ln:      LN + residual out (R2 version)

typedef __attribute__((ext_vector_type(8))) short short8;
typedef __attribute__((ext_vector_type(4))) float floatx4;

__device__ __forceinline__ unsigned pack_bf16(float re, float im) {
  unsigned a = __float_as_uint(re), b = __float_as_uint(im);
  a = (a + 0x7FFFu + ((a >> 16) & 1u)) >> 16;
  b = (b + 0x7FFFu + ((b >> 16) & 1u)) >> 16;
  return a | (b << 16);
}
__device__ __forceinline__ unsigned short bf16r(float v) {
  unsigned a = __float_as_uint(v);
  return (unsigned short)((a + 0x7FFFu + ((a >> 16) & 1u)) >> 16);
}

// ------------------------------------------------------------- k_mixprep
__global__ __launch_bounds__(256) void k_mixprep(
    const float* __restrict__ x, const float* __restrict__ pWr,
    const float* __restrict__ pWi,
    const float* __restrict__ U_re, const float* __restrict__ U_im,
    const float* __restrict__ V_re, const float* __restrict__ V_im,
    const float* __restrict__ projc_w, const float* __restrict__ convr_w,
    const float* __restrict__ convi_w,
    const float* __restrict__ listT, const float* __restrict__ plb,
    const float* __restrict__ dmod, const float* __restrict__ W1,
    const float* __restrict__ b1, const float* __restrict__ W2,
    const float* __restrict__ b2, const float* __restrict__ fscale,
    unsigned* __restrict__ hs, unsigned* __restrict__ zqA,
    unsigned* __restrict__ recA, unsigned* __restrict__ recB,
    unsigned* __restrict__ Wtb, float2* __restrict__ lam,
    float* __restrict__ gam) {
  __shared__ __align__(16) char smem[33280];
  const int tid = threadIdx.x;
  const int bid = blockIdx.x;
  if (bid < 64) {                             // ---------------- ctx + MLP
    float* cred = (float*)smem;               // [32][8]
    float* ctxs = cred + 256;                 // [32]
    float* mid_s = ctxs + 32;                 // [32]
    const int bl = bid;
    {
      int c = tid >> 3, sub = tid & 7;
      const float4* xb = (const float4*)(x + (size_t)bl * 131072 + c * 4096);
      float s = 0.f;
#pragma unroll 8
      for (int m = 0; m < 128; ++m) {
        float4 v = xb[sub + m * 8];
        s += v.x + v.y + v.z + v.w;
      }
      cred[c * 8 + sub] = s;
    }
    __syncthreads();
    if (tid < 32) {
      float t = 0.f;
#pragma unroll
      for (int k = 0; k < 8; ++k) t += cred[tid * 8 + k];
      ctxs[tid] = t * (1.f / 4096.f);
    }
    __syncthreads();
    float dt = listT[bl];
    if (tid < 32) {
      float a = b1[tid];
      for (int j = 0; j < 32; ++j) a += ctxs[j] * W1[j * 32 + tid];
      a += dt * W1[1024 + tid];
      mid_s[tid] = tanhf(a);
    }
    __syncthreads();
    float fs = fscale[0];
#pragma unroll
    for (int u = 0; u < 4; ++u) {
      int cr = u * 256 + tid;
      int col = cr * 2;
      float m0 = b2[col], m1 = b2[col + 1];
      for (int h = 0; h < 32; ++h) {
        float mh = mid_s[h];
        float2 w2 = *(const float2*)&W2[h * 2048 + col];
        m0 += mh * w2.x;
        m1 += mh * w2.y;
      }
      float dnu = fs * tanhf(m0);
      float dth = fs * tanhf(m1);
      float nub = expf(plb[cr] + dmod[cr]);
      float thb = expf(plb[1024 + cr] + dmod[1024 + cr]);
      float nut = fmaxf(nub * dt + dnu, 1e-6f);
      float tht = thb * dt + dth;
      float e = expf(-nut);
      float sa, ca;
      sincosf(tht, &sa, &ca);
      float g = sqrtf(fmaxf(1.f - expf(-2.f * nut), 1e-12f));
      int o = bl * 1024 + cr;
      lam[o] = make_float2(e * ca, e * sa);
      gam[o] = g;
    }
  } else if (bid < 1088) {                    // ---------------- mix body
    unsigned* xb_s = (unsigned*)smem;         // [256*20] 20 KB
    unsigned* outb = (unsigned*)smem;         // [32][260] 33 KB
    const int wk = bid - 64;
    const int bl = wk >> 4;
    const int seg = wk & 15;
    const int pxbase = seg * 256;
    const float* xb = x + (size_t)bl * 131072 + pxbase;
#pragma unroll
    for (int t = 0; t < 4; ++t) {
      int i = t * 256 + tid;
      int c2 = i & 15, g4 = i >> 4;
      float4 a = *(const float4*)(xb + (2 * c2) * 4096 + g4 * 4);
      float4 b = *(const float4*)(xb + (2 * c2 + 1) * 4096 + g4 * 4);
#pragma unroll
      for (int j = 0; j < 4; ++j) {
        int px = g4 * 4 + j;
        xb_s[px * 20 + (((c2 >> 2) ^ (px & 3)) << 2) + (c2 & 3)] =
            pack_bf16(((const float*)&a)[j], ((const float*)&b)[j]);
      }
    }
    const int lane = tid & 63, wv = tid >> 6;
    const int qd = lane >> 4, ln = lane & 15;
    short8 arL, aiL, arH, aiH;
#pragma unroll
    for (int j = 0; j < 8; ++j) {
      int ci = qd * 8 + j;
      ((short*)&arL)[j] = (short)bf16r(pWr[ci * 32 + ln]);
      ((short*)&aiL)[j] = (short)bf16r(pWi[ci * 32 + ln]);
      ((short*)&arH)[j] = (short)bf16r(pWr[ci * 32 + 16 + ln]);
      ((short*)&aiH)[j] = (short)bf16r(pWi[ci * 32 + 16 + ln]);
    }
    __syncthreads();
    floatx4 RL[4], IL[4], RH[4], IH[4];
#pragma unroll
    for (int pt = 0; pt < 4; ++pt) {
      int pxt = wv * 4 + pt;
      int pxl = pxt * 16 + ln;
      short8 bfr = *(const short8*)&xb_s[pxl * 20 + ((qd ^ (pxl & 3)) << 2)];
      floatx4 z4 = {0.f, 0.f, 0.f, 0.f};
      RL[pt] = __builtin_amdgcn_mfma_f32_16x16x32_bf16(arL, bfr, z4, 0, 0, 0);
      IL[pt] = __builtin_amdgcn_mfma_f32_16x16x32_bf16(aiL, bfr, z4, 0, 0, 0);
      RH[pt] = __builtin_amdgcn_mfma_f32_16x16x32_bf16(arH, bfr, z4, 0, 0, 0);
      IH[pt] = __builtin_amdgcn_mfma_f32_16x16x32_bf16(aiH, bfr, z4, 0, 0, 0);
    }
    __syncthreads();                          // xb_s dead; reuse as outb
#pragma unroll
    for (int pt = 0; pt < 4; ++pt) {
      int px = (wv * 4 + pt) * 16 + ln;
#pragma unroll
      for (int j = 0; j < 4; ++j) {
        outb[(qd * 4 + j) * 260 + px] = pack_bf16(RL[pt][j], IL[pt][j]);
        outb[(16 + qd * 4 + j) * 260 + px] = pack_bf16(RH[pt][j], IH[pt][j]);
      }
    }
    __syncthreads();
    unsigned* ho = hs + (size_t)bl * 131072 + pxbase;
    const int px4 = tid & 63, dg = tid >> 6;
#pragma unroll
    for (int dd = 0; dd < 8; ++dd) {
      int d = dg * 8 + dd;
      uint4 v = *(const uint4*)&outb[d * 260 + px4 * 4];
      *(uint4*)(ho + d * 4096 + px4 * 4) = v;
    }
  } else if (bid < 1152) {                    // ---------------- DFT body
    float2* A2 = (float2*)smem;               // [2048] 16 KB
    float2* tw = (float2*)(smem + 16384);     // [64]
    const int id = bid - 1088;
    const int c = id >> 1, src = id & 1;      // 0=U(plus), 1=V(minus)
    const float* Ar = (src ? V_re : U_re) + c * 2048;
    const float* Ai = (src ? V_im : U_im) + c * 2048;
    if (tid < 64) {
      float sa, ca;
      sincosf((float)tid * 0.09817477042468103f, &sa, &ca);
      tw[tid] = make_float2(ca, sa);
    }
#pragma unroll
    for (int t = 0; t < 8; ++t) {
      int idx = t * 256 + tid;
      A2[idx] = make_float2(Ar[idx], Ai[idx]);
    }
    __syncthreads();
    const int kw = tid >> 2, mg = tid & 3;
    float sr[8] = {0.f, 0.f, 0.f, 0.f, 0.f, 0.f, 0.f, 0.f};
    float si[8] = {0.f, 0.f, 0.f, 0.f, 0.f, 0.f, 0.f, 0.f};
#pragma unroll 4
    for (int n = 0; n < 64; ++n) {
      float2 w = tw[(kw * n) & 63];
      float ws = src ? -w.y : w.y;
#pragma unroll
      for (int t4 = 0; t4 < 4; ++t4) {
        float4 q = *(const float4*)&A2[n * 32 + mg * 8 + t4 * 2];
        sr[2 * t4]     += q.x * w.x - q.y * ws;
        si[2 * t4]     += q.x * ws + q.y * w.x;
        sr[2 * t4 + 1] += q.z * w.x - q.w * ws;
        si[2 * t4 + 1] += q.z * ws + q.w * w.x;
      }
    }
#pragma unroll
    for (int j = 0; j < 8; ++j) {
      float r = sr[j] * 0.125f, i2 = si[j] * 0.125f;
      int m = mg * 8 + j;
      unsigned p_ri  = pack_bf16(r, i2);
      unsigned p_rmi = pack_bf16(r, -i2);
      unsigned p_ir  = pack_bf16(i2, r);
      unsigned p_mir = pack_bf16(-i2, r);
      if (src == 0) {                         // F+ . U
        zqA[((c * 4 + 2) * 32 + m) * 64 + kw] = p_ri;   // A3
        zqA[((c * 4 + 3) * 32 + m) * 64 + kw] = p_mir;  // A4
        recA[((c * 2 + 0) * 64 + kw) * 32 + m] = p_rmi; // A5
        recA[((c * 2 + 1) * 64 + kw) * 32 + m] = p_ir;  // A6
      } else {                                // F- . V
        zqA[((c * 4 + 0) * 32 + m) * 64 + kw] = p_rmi;  // A1
        zqA[((c * 4 + 1) * 32 + m) * 64 + kw] = p_ir;   // A2
        recB[((c * 2 + 0) * 64 + kw) * 32 + m] = p_ri;  // B5
        recB[((c * 2 + 1) * 64 + kw) * 32 + m] = p_mir; // B6
      }
    }
  } else {                                    // ---------------- weff body
    int gid = (bid - 1152) * 256 + tid;       // (co*9+tap)*32 + ci
    if (gid < 9216) {
      int co = gid / 288;
      int r2 = gid - co * 288;
      int tap = r2 >> 5, ci = r2 & 31;
      float sr = 0.f, si = 0.f;
      for (int m = 0; m < 32; ++m) {
        sr += projc_w[co * 64 + m]      * convr_w[(m * 32 + ci) * 9 + tap];
        si += projc_w[co * 64 + 32 + m] * convi_w[(m * 32 + ci) * 9 + tap];
      }
      Wtb[gid] = pack_bf16(sr, si);
    }
  }
}

// ------------------------------------------------------------- k_mid
// 64 blocks (b,c) x 512 threads (2 wave-groups of 4). Per round: group g
// handles l = 2*round+g: zq GEMM1/GEMM2 -> both groups run the exact
// sequential scan (redundant, deterministic) -> rec GEMM1/GEMM2 -> hsp.
// Next round's hs is staged during rec GEMM2. All intermediates in LDS.
__global__ __launch_bounds__(512, 2) void k_mid(
    const unsigned* __restrict__ hs, const short* __restrict__ zqA,
    const short* __restrict__ recA, const short* __restrict__ recB,
    const float2* __restrict__ lam, const float* __restrict__ gam,
    unsigned* __restrict__ hsp) {
  __shared__ __align__(16) char smem[61440];
  float2* lam_s = (float2*)smem;                  // [32][32] 8 KB
  float*  gam_s = (float*)(smem + 8192);          // [32][32] 4 KB
  unsigned* HsB = (unsigned*)(smem + 12288);      // [2][4096] 32 KB
  float2* zqt   = (float2*)(smem + 12288);        // [2][1024] (alias HsB g0)
  unsigned* zB  = (unsigned*)(smem + 28672);      // [2][1024] (alias HsB g1)
  unsigned* T2P = (unsigned*)(smem + 45056);      // [2][2048] 16 KB
  const int tid = threadIdx.x;
  const int b = blockIdx.x >> 5, c = blockIdx.x & 31;
  const int lane = tid & 63, wv = tid >> 6;
  const int grp = wv >> 2, wvg = wv & 3;
  const int tg = tid & 255;
  const int qd = lane >> 4, ln = lane & 15;
  const int mt = wvg >> 1, nth = wvg & 1;
  // block-invariant coefficient fragments
  const short* zA = zqA + (size_t)c * 4 * 32 * 128;
  short8 a1[4], a2[4], a3[4], a4[4];
#pragma unroll
  for (int t = 0; t < 4; ++t) {
    int row = mt * 16 + ln;
    a1[t] = *(const short8*)(zA + (0 * 32 + row) * 128 + t * 32 + qd * 8);
    a2[t] = *(const short8*)(zA + (1 * 32 + row) * 128 + t * 32 + qd * 8);
    a3[t] = *(const short8*)(zA + (2 * 32 + row) * 128 + t * 32 + qd * 8);
    a4[t] = *(const short8*)(zA + (3 * 32 + row) * 128 + t * 32 + qd * 8);
  }
  const short* rA = recA + (size_t)c * 2 * 64 * 64;
  short8 a5[2], a6[2];
#pragma unroll
  for (int t = 0; t < 2; ++t) {
    int row = wvg * 16 + ln;
    a5[t] = *(const short8*)(rA + (0 * 64 + row) * 64 + t * 32 + qd * 8);
    a6[t] = *(const short8*)(rA + (1 * 64 + row) * 64 + t * 32 + qd * 8);
  }
  const short* rB = recB + (size_t)c * 2 * 64 * 64;
  // stage lam/gam for all (l, r) of this (b,c)
  for (int idx = tid; idx < 1024; idx += 512) {
    int l = idx >> 5, r = idx & 31;
    lam_s[idx] = lam[(b * 32 + l) * 1024 + c * 32 + r];
    gam_s[idx] = gam[(b * 32 + l) * 1024 + c * 32 + r];
  }
  // initial hs stage (l = grp)
  {
    const uint4* hp =
        (const uint4*)(hs + (size_t)((b * 32 + grp) * 32 + c) * 4096);
#pragma unroll
    for (int it = 0; it < 4; ++it) {
      int i4 = tg + it * 256;
      uint4 v = hp[i4];
      int s = i4 >> 4, w4 = i4 & 15;
      *(uint4*)&HsB[grp * 4096 + s * 64 + ((w4 ^ (s & 15)) << 2)] = v;
    }
  }
  float2 st[4];
#pragma unroll
  for (int j = 0; j < 4; ++j) st[j] = make_float2(0.f, 0.f);
  __syncthreads();
  for (int round = 0; round < 16; ++round) {
    const int l0 = round * 2;
    const int blc = (b * 32 + l0 + grp) * 32 + c;
    // ---- zq GEMM1: T2[q][s]
#pragma unroll
    for (int nti = 0; nti < 2; ++nti) {
      int nt = nth * 2 + nti;
      int n = nt * 16 + ln;
      floatx4 accr = {0.f, 0.f, 0.f, 0.f}, acci = {0.f, 0.f, 0.f, 0.f};
#pragma unroll
      for (int t = 0; t < 4; ++t) {
        short8 bb = *(const short8*)&HsB[grp * 4096 + n * 64 +
                                         (((4 * t + qd) ^ (n & 15)) << 2)];
        accr = __builtin_amdgcn_mfma_f32_16x16x32_bf16(a1[t], bb, accr, 0, 0, 0);
        acci = __builtin_amdgcn_mfma_f32_16x16x32_bf16(a2[t], bb, acci, 0, 0, 0);
      }
#pragma unroll
      for (int j = 0; j < 4; ++j) {
        int q = mt * 16 + qd * 4 + j;
        int s = n;
        T2P[grp * 2048 + q * 64 + (((s >> 2) ^ (q & 15)) << 2) + (s & 3)] =
            pack_bf16(accr[j], acci[j]);
      }
    }
    __syncthreads();
    // ---- zq GEMM2 -> zqt (fp32)
    {
      int n = nth * 16 + ln;
      floatx4 zr = {0.f, 0.f, 0.f, 0.f}, zi = {0.f, 0.f, 0.f, 0.f};
#pragma unroll
      for (int t = 0; t < 4; ++t) {
        short8 bb = *(const short8*)&T2P[grp * 2048 + n * 64 +
                                         (((4 * t + qd) ^ (n & 15)) << 2)];
        zr = __builtin_amdgcn_mfma_f32_16x16x32_bf16(a3[t], bb, zr, 0, 0, 0);
        zi = __builtin_amdgcn_mfma_f32_16x16x32_bf16(a4[t], bb, zi, 0, 0, 0);
      }
#pragma unroll
      for (int j = 0; j < 4; ++j) {
        int r = mt * 16 + qd * 4 + j;
        zqt[grp * 1024 + r * 32 + n] = make_float2(zr[j], zi[j]);
      }
    }
    __syncthreads();
    // ---- scan (both groups, redundant+deterministic) + zB write
    {
      int q = nth * 16 + ln;
#pragma unroll
      for (int j = 0; j < 4; ++j) {
        int r = mt * 16 + qd * 4 + j;
        float2 lm = lam_s[l0 * 32 + r];
        float g = gam_s[l0 * 32 + r];
        float2 v = zqt[r * 32 + q];
        float nr = lm.x * st[j].x - lm.y * st[j].y + g * v.x;
        float ni = lm.x * st[j].y + lm.y * st[j].x + g * v.y;
        st[j] = make_float2(nr, ni);
        unsigned pk = pack_bf16(nr, ni);
        lm = lam_s[(l0 + 1) * 32 + r];
        g = gam_s[(l0 + 1) * 32 + r];
        v = zqt[1024 + r * 32 + q];
        nr = lm.x * st[j].x - lm.y * st[j].y + g * v.x;
        ni = lm.x * st[j].y + lm.y * st[j].x + g * v.y;
        st[j] = make_float2(nr, ni);
        if (grp) pk = pack_bf16(nr, ni);
        zB[grp * 1024 + q * 32 + (((r >> 2) ^ (q & 7)) << 2) + (r & 3)] = pk;
      }
    }
    __syncthreads();
    // ---- rec GEMM1 -> P
#pragma unroll
    for (int nt = 0; nt < 2; ++nt) {
      int n = nt * 16 + ln;
      floatx4 pr = {0.f, 0.f, 0.f, 0.f}, pi = {0.f, 0.f, 0.f, 0.f};
#pragma unroll
      for (int t = 0; t < 2; ++t) {
        short8 bb = *(const short8*)&zB[grp * 1024 + n * 32 +
                                        (((4 * t + qd) ^ (n & 7)) << 2)];
        pr = __builtin_amdgcn_mfma_f32_16x16x32_bf16(a5[t], bb, pr, 0, 0, 0);
        pi = __builtin_amdgcn_mfma_f32_16x16x32_bf16(a6[t], bb, pi, 0, 0, 0);
      }
#pragma unroll
      for (int j = 0; j < 4; ++j) {
        int s = wvg * 16 + qd * 4 + j;
        int q = n;
        T2P[grp * 2048 + s * 32 + (((q >> 2) ^ (s & 7)) << 2) + (q & 3)] =
            pack_bf16(pr[j], pi[j]);
      }
    }
    __syncthreads();
    // ---- stage next hs (loads early) + rec GEMM2 -> hsp
    uint4 sv[4];
    const bool more = (round < 15);
    if (more) {
      const uint4* hp = (const uint4*)(
          hs + (size_t)((b * 32 + l0 + 2 + grp) * 32 + c) * 4096);
#pragma unroll
      for (int it = 0; it < 4; ++it) sv[it] = hp[tg + it * 256];
    }
    {
      short8 pa[2];
      int row = wvg * 16 + ln;
#pragma unroll
      for (int t = 0; t < 2; ++t)
        pa[t] = *(const short8*)&T2P[grp * 2048 + row * 32 +
                                     (((4 * t + qd) ^ (row & 7)) << 2)];
      unsigned* ho = hsp + (size_t)blc * 4096;
#pragma unroll
      for (int nt = 0; nt < 4; ++nt) {
        int n = nt * 16 + ln;
        floatx4 hr = {0.f, 0.f, 0.f, 0.f}, hi = {0.f, 0.f, 0.f, 0.f};
#pragma unroll
        for (int t = 0; t < 2; ++t) {
          short8 b5 = *(const short8*)(rB + (0 * 64 + n) * 64 + t * 32 + qd * 8);
          short8 b6 = *(const short8*)(rB + (1 * 64 + n) * 64 + t * 32 + qd * 8);
          hr = __builtin_amdgcn_mfma_f32_16x16x32_bf16(pa[t], b5, hr, 0, 0, 0);
          hi = __builtin_amdgcn_mfma_f32_16x16x32_bf16(pa[t], b6, hi, 0, 0, 0);
        }
#pragma unroll
        for (int j = 0; j < 4; ++j) {
          int s = wvg * 16 + qd * 4 + j;
          ho[s * 64 + n] = pack_bf16(hr[j], hi[j]);
        }
      }
    }
    if (more) {
#pragma unroll
      for (int it = 0; it < 4; ++it) {
        int i4 = tg + it * 256;
        int s = i4 >> 4, w4 = i4 & 15;
        *(uint4*)&HsB[grp * 4096 + s * 64 + ((w4 ^ (s & 15)) << 2)] = sv[it];
      }
    }
    __syncthreads();
  }
}

// ------------------------------------------------------------ MFMA 3x3 conv
__global__ __launch_bounds__(256, 2) void k_conv(
    const unsigned* __restrict__ hsp, const short* __restrict__ Wtb,
    unsigned short* __restrict__ convout, float2* __restrict__ stats) {
  __shared__ unsigned lds_in[6 * 66 * 32];   // 50,688 B
  const int bl = blockIdx.x >> 4;
  const int slab = blockIdx.x & 15;
  const int y0 = slab * 4;
  const int tid = threadIdx.x;
  for (int i = tid; i < 384; i += 256) {     // zero x-border cells
    int ci = i & 31, j = i >> 5;
    int yi = j >> 1, xi = (j & 1) ? 65 : 0;
    int slot = (ci >> 2) ^ (xi & 7);
    lds_in[(yi * 66 + xi) * 32 + slot * 4 + (ci & 3)] = 0u;
  }
#pragma unroll
  for (int t = 0; t < 12; ++t) {             // interior staging
    int i = t * 256 + tid;
    int ci = i & 31;
    int j = i >> 5;
    int yi = j >> 4, x4 = j & 15;
    int y = y0 + yi - 1;
    uint4 v = make_uint4(0u, 0u, 0u, 0u);
    if ((unsigned)y < 64u)
      v = *(const uint4*)(hsp + (((size_t)bl * 32 + ci) * 64 + y) * 64 + x4 * 4);
    int xb = 1 + x4 * 4;
#pragma unroll
    for (int jj = 0; jj < 4; ++jj) {
      int xi = xb + jj;
      int slot = (ci >> 2) ^ (xi & 7);
      lds_in[(yi * 66 + xi) * 32 + slot * 4 + (ci & 3)] =
          ((const unsigned*)&v)[jj];
    }
  }
  const int lane = tid & 63;
  const int wv = tid >> 6;
  const int co = lane & 15;
  const int qd = lane >> 4;
  short8 bL[18], bH[18];
  {
    const short* wpL = Wtb + (co * 9) * 64 + qd * 8;
    const short* wpH = Wtb + ((co + 16) * 9) * 64 + qd * 8;
#pragma unroll
    for (int tap = 0; tap < 9; ++tap)
#pragma unroll
      for (int kk = 0; kk < 2; ++kk) {
        bL[tap * 2 + kk] = *(const short8*)(wpL + tap * 64 + kk * 32);
        bH[tap * 2 + kk] = *(const short8*)(wpH + tap * 64 + kk * 32);
      }
  }
  __syncthreads();
  float sL = 0.f, s2L = 0.f, sH = 0.f, s2H = 0.f;
  const int x0 = wv * 16;
  const int xl = lane & 15;
  for (int ry = 0; ry < 4; ++ry) {
    floatx4 aL = {0.f, 0.f, 0.f, 0.f}, aH = {0.f, 0.f, 0.f, 0.f};
#pragma unroll
    for (int tap = 0; tap < 9; ++tap) {
      int dy = tap / 3, dx = tap - dy * 3;
      int yi = ry + dy;
      int xi = x0 + xl + dx;
#pragma unroll
      for (int kk = 0; kk < 2; ++kk) {
        int slot = ((kk << 2) | qd) ^ (xi & 7);
        const short8 a =
            *(const short8*)&lds_in[(yi * 66 + xi) * 32 + slot * 4];
        aL = __builtin_amdgcn_mfma_f32_16x16x32_bf16(a, bL[tap * 2 + kk], aL, 0, 0, 0);
        aH = __builtin_amdgcn_mfma_f32_16x16x32_bf16(a, bH[tap * 2 + kk], aH, 0, 0, 0);
      }
    }
    size_t goL = (((size_t)bl * 32 + co) * 64 + (y0 + ry)) * 64 + x0 + qd * 4;
    size_t goH = goL + (size_t)16 * 4096;
    *(uint2*)(convout + goL) =
        make_uint2(pack_bf16(aL[0], aL[1]), pack_bf16(aL[2], aL[3]));
    *(uint2*)(convout + goH) =
        make_uint2(pack_bf16(aH[0], aH[1]), pack_bf16(aH[2], aH[3]));
#pragma unroll
    for (int j = 0; j < 4; ++j) {
      sL += aL[j]; s2L += aL[j] * aL[j];
      sH += aH[j]; s2H += aH[j] * aH[j];
    }
  }
  sL += __shfl_down(sL, 32, 64);  s2L += __shfl_down(s2L, 32, 64);
  sH += __shfl_down(sH, 32, 64);  s2H += __shfl_down(s2H, 32, 64);
  sL += __shfl_down(sL, 16, 64);  s2L += __shfl_down(s2L, 16, 64);
  sH += __shfl_down(sH, 16, 64);  s2H += __shfl_down(s2H, 16, 64);
  if (lane < 16) {
    stats[((size_t)bl * 32 + lane) * 64 + slab * 4 + wv] = make_float2(sL, s2L);
    stats[((size_t)bl * 32 + 16 + lane) * 64 + slab * 4 + wv] =
        make_float2(sH, s2H);
  }
}

// -------------------------------------------------------- LN + residual out
__global__ __launch_bounds__(256) void k_ln(
    const unsigned short* __restrict__ convout,
    const float2* __restrict__ stats, const float* __restrict__ x,
    const float* __restrict__ ln_w, const float* __restrict__ ln_b,
    float* __restrict__ out) {
  const int blc = blockIdx.x;
  const int tid = threadIdx.x;
  __shared__ float sh_mu, sh_rs;
  if (tid < 64) {
    float2 v = stats[(size_t)blc * 64 + tid];
    float s = v.x, s2 = v.y;
#pragma unroll
    for (int o = 32; o > 0; o >>= 1) {
      s += __shfl_down(s, o, 64);
      s2 += __shfl_down(s2, o, 64);
    }
    if (tid == 0) {
      float mu = s * (1.f / 4096.f);
      float var = s2 * (1.f / 4096.f) - mu * mu;
      sh_mu = mu;
      sh_rs = rsqrtf(var + 1e-5f);
    }
  }
  __syncthreads();
  float mu = sh_mu, rs = sh_rs;
  const uint2* cp = (const uint2*)(convout + (size_t)blc * 4096);
  const float4* xp = (const float4*)(x + (size_t)blc * 4096);
  const float4* lwp = (const float4*)ln_w;
  const float4* lbp = (const float4*)ln_b;
  float4* op = (float4*)(out + (size_t)blc * 4096);
#pragma unroll
  for (int k = 0; k < 4; ++k) {
    int i = tid + k * 256;
    uint2 cv = cp[i];
    float4 xv = xp[i], lw = lwp[i], lb = lbp[i];
    float c0 = __uint_as_float(cv.x << 16);
    float c1 = __uint_as_float(cv.x & 0xFFFF0000u);
    float c2 = __uint_as_float(cv.y << 16);
    float c3 = __uint_as_float(cv.y & 0xFFFF0000u);
    float4 o;
    o.x = xv.x + (c0 - mu) * rs * lw.x + lb.x;
    o.y = xv.y + (c1 - mu) * rs * lw.y + lb.y;
    o.z = xv.z + (c2 - mu) * rs * lw.z + lb.z;
    o.w = xv.w + (c3 - mu) * rs * lw.w + lb.w;
    op[i] = o;
  }
}

// ------------------------------------------------------------------- launch
extern "C" void kernel_launch(void* const* d_in, const int* in_sizes, int n_in,
                              void* d_out, int out_size, void* d_ws,
                              size_t ws_size, hipStream_t stream) {
  const float* x       = (const float*)d_in[0];
  const float* listT   = (const float*)d_in[1];
  const float* plb     = (const float*)d_in[2];
  const float* dmod    = (const float*)d_in[3];
  const float* fm_W1   = (const float*)d_in[4];
  const float* fm_b1   = (const float*)d_in[5];
  const float* fm_W2   = (const float*)d_in[6];
  const float* fm_b2   = (const float*)d_in[7];
  const float* fscale  = (const float*)d_in[8];
  const float* U_re    = (const float*)d_in[9];
  const float* U_im    = (const float*)d_in[10];
  const float* V_re    = (const float*)d_in[11];
  const float* V_im    = (const float*)d_in[12];
  const float* pW_re   = (const float*)d_in[13];
  const float* pW_im   = (const float*)d_in[14];
  // d_in[15..16] pb_re/pb_im: cropped out, no effect
  const float* convr_w = (const float*)d_in[17];
  // convr_b/convi_b/projc_b (18,20,22): constant over [S,W] -> cancel in LN
  const float* convi_w = (const float*)d_in[19];
  const float* projc_w = (const float*)d_in[21];
  const float* ln_w    = (const float*)d_in[23];
  const float* ln_b    = (const float*)d_in[24];
  float* out = (float*)d_out;

  float* wsf = (float*)d_ws;
  unsigned* hs   = (unsigned*)wsf;                        // [0, 8388608)
  unsigned* hsp  = (unsigned*)(wsf + 8388608);            // [8388608, 16777216)
  unsigned* zqAp = (unsigned*)(wsf + 16777216);           // 262144 u32
  unsigned* recAp = (unsigned*)(wsf + 17039360);          // 131072 u32
  unsigned* recBp = (unsigned*)(wsf + 17170432);          // 131072 u32
  unsigned short* convout = (unsigned short*)(wsf + 17301504);  // 8388608 u16
  float2*   stats = (float2*)(wsf + 25690112);            // 131072 float2
  float2*   lam   = (float2*)(wsf + 25952256);            // 65536 float2
  float*    gam   = wsf + 26083328;                       // 65536 fl
  unsigned* Wtb   = (unsigned*)(wsf + 26148864);          // 9216 u32

  k_mixprep<<<1188, 256, 0, stream>>>(x, pW_re, pW_im, U_re, U_im, V_re, V_im,
                                      projc_w, convr_w, convi_w, listT, plb,
                                      dmod, fm_W1, fm_b1, fm_W2, fm_b2, fscale,
                                      hs, zqAp, recAp, recBp, Wtb, lam, gam);
  k_mid<<<64, 512, 0, stream>>>(hs, (const short*)zqAp, (const short*)recAp,
                                (const short*)recBp, lam, gam, hsp);
  k_conv<<<1024, 256, 0, stream>>>(hsp, (const short*)Wtb, convout, stats);
  k_ln<<<2048, 256, 0, stream>>>(convout, stats, x, ln_w, ln_b, out);
}